// Round 1
// 7179.870 us; speedup vs baseline: 1.9198x; 1.9198x over previous
//
#include <hip/hip_runtime.h>

#define TT 512
#define BB 64
#define HH 1024
#define G4 4096

typedef _Float16 h8 __attribute__((ext_vector_type(8)));
typedef float f4 __attribute__((ext_vector_type(4)));

// ---------------- prep kernels ----------------

// W_ih fp32 -> fp16, flat copy. 4096*1024 elems, 8 per thread.
__global__ void k_conv_wih(const float* __restrict__ w, _Float16* __restrict__ o) {
  int i = blockIdx.x * 256 + threadIdx.x;          // 0..524287
  const f4* src = (const f4*)w + (size_t)i * 2;
  f4 a = src[0], b = src[1];
  h8 r;
  r[0] = (_Float16)a[0]; r[1] = (_Float16)a[1]; r[2] = (_Float16)a[2]; r[3] = (_Float16)a[3];
  r[4] = (_Float16)b[0]; r[5] = (_Float16)b[1]; r[6] = (_Float16)b[2]; r[7] = (_Float16)b[3];
  *(h8*)(o + (size_t)i * 8) = r;
}

// W_hh fp32 [4096,1024] -> fp16 shuffled into MFMA B-fragment order:
// block b = nt*32 + kt holds lane l's 8 halves W[nt*16 + (l&15)][kt*32 + (l>>4)*8 + j]
// so phase B's per-(wave,kt) load is one fully coalesced 1KB global_load_dwordx4.
__global__ void k_shuf_whh(const float* __restrict__ w, _Float16* __restrict__ o) {
  int cidx = blockIdx.x * 256 + threadIdx.x;       // 0..524287
  int b = cidx >> 6;                               // 0..8191 (256 nt * 32 kt)
  int lid = cidx & 63;
  int n = (b >> 5) * 16 + (lid & 15);
  int k0 = (b & 31) * 32 + (lid >> 4) * 8;
  const float* src = w + (size_t)n * HH + k0;
  h8 r;
  #pragma unroll
  for (int j = 0; j < 8; ++j) r[j] = (_Float16)src[j];
  *(h8*)(o + (size_t)b * 512 + lid * 8) = r;
}

__global__ void k_bsum(const float* __restrict__ bi, const float* __restrict__ bh,
                       float* __restrict__ o) {
  int i = blockIdx.x * 256 + threadIdx.x;          // 4096
  o[i] = bi[i] + bh[i];
}

// h0 fp32 -> fp16 into hbuf[0]; zero the flag array (ws is poisoned each launch).
__global__ void k_prep(const float* __restrict__ h0, _Float16* __restrict__ hbuf,
                       unsigned* __restrict__ bar) {
  int i = blockIdx.x * 256 + threadIdx.x;          // 65536
  hbuf[i] = (_Float16)h0[i];
  if (i < 2048) bar[i] = 0u;                       // 64 flags @ 128B stride
}

// ---------------- phase A: gates_x = x @ W_ih^T + (b_ih + b_hh) ----------------
// M=32768, N=4096, K=1024. 128x128 tile per 256-thread wg, BK=32, fp16 MFMA.
__global__ __launch_bounds__(256) void k_gemm_gx(
    const float* __restrict__ x, const _Float16* __restrict__ wih,
    const float* __restrict__ bsum, _Float16* __restrict__ gx) {
  __shared__ _Float16 As[128 * 40];   // pad 32->40 halves: 2-way banks only (free)
  __shared__ _Float16 Bs[128 * 40];
  const int bid = blockIdx.x;
  const int m0 = (bid >> 5) * 128;
  const int n0 = (bid & 31) * 128;
  const int tid = threadIdx.x;
  const int w = tid >> 6, l = tid & 63, q = l >> 4, lj = l & 15;
  const int wm = (w >> 1) * 64, wn = (w & 1) * 64;
  const int lrow = tid >> 1;
  const int lcol = (tid & 1) * 16;

  f4 z = {0.f, 0.f, 0.f, 0.f};
  f4 acc[4][4];
  #pragma unroll
  for (int i2 = 0; i2 < 4; ++i2)
    #pragma unroll
    for (int j2 = 0; j2 < 4; ++j2) acc[i2][j2] = z;

  for (int kt = 0; kt < 32; ++kt) {
    const int k0 = kt * 32;
    const float* xp = x + (size_t)(m0 + lrow) * HH + k0 + lcol;
    f4 a0 = ((const f4*)xp)[0];
    f4 a1 = ((const f4*)xp)[1];
    f4 a2 = ((const f4*)xp)[2];
    f4 a3 = ((const f4*)xp)[3];
    const _Float16* bp = wih + (size_t)(n0 + lrow) * HH + k0 + lcol;
    h8 b0 = ((const h8*)bp)[0];
    h8 b1 = ((const h8*)bp)[1];
    h8 lo, hi;
    lo[0] = (_Float16)a0[0]; lo[1] = (_Float16)a0[1]; lo[2] = (_Float16)a0[2]; lo[3] = (_Float16)a0[3];
    lo[4] = (_Float16)a1[0]; lo[5] = (_Float16)a1[1]; lo[6] = (_Float16)a1[2]; lo[7] = (_Float16)a1[3];
    hi[0] = (_Float16)a2[0]; hi[1] = (_Float16)a2[1]; hi[2] = (_Float16)a2[2]; hi[3] = (_Float16)a2[3];
    hi[4] = (_Float16)a3[0]; hi[5] = (_Float16)a3[1]; hi[6] = (_Float16)a3[2]; hi[7] = (_Float16)a3[3];
    __syncthreads();
    *(h8*)&As[lrow * 40 + lcol] = lo;
    *(h8*)&As[lrow * 40 + lcol + 8] = hi;
    *(h8*)&Bs[lrow * 40 + lcol] = b0;
    *(h8*)&Bs[lrow * 40 + lcol + 8] = b1;
    __syncthreads();
    h8 af[4], bf[4];
    #pragma unroll
    for (int mt = 0; mt < 4; ++mt) af[mt] = *(h8*)&As[(wm + mt * 16 + lj) * 40 + q * 8];
    #pragma unroll
    for (int nt = 0; nt < 4; ++nt) bf[nt] = *(h8*)&Bs[(wn + nt * 16 + lj) * 40 + q * 8];
    #pragma unroll
    for (int mt = 0; mt < 4; ++mt)
      #pragma unroll
      for (int nt = 0; nt < 4; ++nt)
        acc[mt][nt] = __builtin_amdgcn_mfma_f32_16x16x32_f16(af[mt], bf[nt], acc[mt][nt], 0, 0, 0);
  }
  // epilogue: add bias, store fp16. C/D layout: col=lane&15, row=(lane>>4)*4+reg.
  #pragma unroll
  for (int nt = 0; nt < 4; ++nt) {
    int n = n0 + wn + nt * 16 + lj;
    float bv = bsum[n];
    #pragma unroll
    for (int mt = 0; mt < 4; ++mt) {
      #pragma unroll
      for (int r = 0; r < 4; ++r) {
        int m = m0 + wm + mt * 16 + q * 4 + r;
        gx[(size_t)m * G4 + n] = (_Float16)(acc[mt][nt][r] + bv);
      }
    }
  }
}

// ---------------- phase B: persistent reverse scan ----------------
// 64 wgs (1/CU), wg s owns h-cols [16s,16s+16); wave w computes gate-type w.
// h ping-pongs in global (fp16); c stays in LDS for the whole scan.
// Grid barrier: DISTRIBUTED FLAGS — each wg release-stores its own flag
// (separate 128B line, no RMW contention), every wg's wave 0 polls all 64
// flags with one 64-lane strided load + __all, then acquire-fences.
__global__ __launch_bounds__(256, 1) void k_lstm_seq(
    const _Float16* __restrict__ gx, const _Float16* __restrict__ wsh,
    const float* __restrict__ c0, float* __restrict__ out,
    _Float16* __restrict__ hbuf, unsigned* __restrict__ bar) {
  __shared__ _Float16 hs[64 * 264];    // h chunk [64 x 256], pad 8 (2-way banks, free)
  __shared__ float gbuf[4 * 64 * 16];  // gate exchange
  __shared__ float cs[64 * 16];        // persistent c slice
  const int tid = threadIdx.x;
  const int s = blockIdx.x;            // 0..63
  const int w = tid >> 6;
  const int l = tid & 63;
  const int q = l >> 4;
  const int lj = l & 15;

  #pragma unroll
  for (int u = 0; u < 4; ++u) {
    int e = u * 256 + tid;             // 0..1023 -> (m = e>>4, j = e&15)
    cs[e] = c0[(size_t)(e >> 4) * HH + s * 16 + (e & 15)];
  }

  for (int ii = 0; ii < TT; ++ii) {
    const int t = TT - 1 - ii;
    const _Float16* __restrict__ hcur = hbuf + (size_t)(ii & 1) * (BB * HH);
    _Float16* __restrict__ hnxt = hbuf + (size_t)((ii + 1) & 1) * (BB * HH);

    // ---- prefetch gx for this step early: cold-HBM latency hides under
    // h staging + GEMM instead of sitting exposed after the GEMM.
    const _Float16* gxb = gx + (size_t)t * BB * G4 + w * HH + s * 16;
    _Float16 gpre[16];
    #pragma unroll
    for (int mt = 0; mt < 4; ++mt)
      #pragma unroll
      for (int r = 0; r < 4; ++r)
        gpre[mt * 4 + r] = gxb[(size_t)(mt * 16 + q * 4 + r) * G4 + lj];

    // ---- prefetch h chunk 0 into registers
    h8 pre[8];
    #pragma unroll
    for (int u = 0; u < 8; ++u) {
      int flat = (u * 256 + tid) * 8;
      pre[u] = *(const h8*)&hcur[(size_t)(flat >> 8) * HH + (flat & 255)];
    }

    f4 z = {0.f, 0.f, 0.f, 0.f};
    f4 acc[4];
    #pragma unroll
    for (int mt = 0; mt < 4; ++mt) acc[mt] = z;

    for (int ck = 0; ck < 4; ++ck) {
      __syncthreads();                 // prior chunk's readers done before overwrite
      #pragma unroll
      for (int u = 0; u < 8; ++u) {
        int flat = (u * 256 + tid) * 8;
        *(h8*)&hs[(flat >> 8) * 264 + (flat & 255)] = pre[u];
      }
      __syncthreads();
      // prefetch chunk ck+1 AFTER the barrier so its latency overlaps the
      // kk MFMA loop (a vmcnt-drain at the barrier would otherwise eat it).
      if (ck < 3) {
        #pragma unroll
        for (int u = 0; u < 8; ++u) {
          int flat = (u * 256 + tid) * 8;
          pre[u] = *(const h8*)&hcur[(size_t)(flat >> 8) * HH + (ck + 1) * 256 + (flat & 255)];
        }
      }
      #pragma unroll
      for (int kk = 0; kk < 8; ++kk) {
        int blk = (w * 64 + s) * 32 + ck * 8 + kk;
        h8 bfr = *(const h8*)&wsh[(size_t)blk * 512 + l * 8];  // coalesced 1KB, L2-hot
        #pragma unroll
        for (int mt = 0; mt < 4; ++mt) {
          h8 afr = *(const h8*)&hs[(mt * 16 + lj) * 264 + kk * 32 + q * 8];
          acc[mt] = __builtin_amdgcn_mfma_f32_16x16x32_f16(afr, bfr, acc[mt], 0, 0, 0);
        }
      }
    }
    // add gates_x (already in registers), exchange via LDS
    #pragma unroll
    for (int mt = 0; mt < 4; ++mt) {
      #pragma unroll
      for (int r = 0; r < 4; ++r) {
        int m = mt * 16 + q * 4 + r;
        float v = acc[mt][r] + (float)gpre[mt * 4 + r];
        gbuf[(w * 64 + m) * 16 + lj] = v;
      }
    }
    __syncthreads();
    // elementwise update: wave w handles rows [w*16, w*16+16)
    const int mbase = w * 16 + q * 4;
    float hv[4], cv[4];
    #pragma unroll
    for (int r = 0; r < 4; ++r) {
      const int m = mbase + r;
      float gi = gbuf[(0 * 64 + m) * 16 + lj];
      float gf = gbuf[(1 * 64 + m) * 16 + lj];
      float gg = gbuf[(2 * 64 + m) * 16 + lj];
      float go = gbuf[(3 * 64 + m) * 16 + lj];
      float iv = 1.f / (1.f + __expf(-gi));
      float fv = 1.f / (1.f + __expf(-gf));
      float gv = tanhf(gg);
      float ov = 1.f / (1.f + __expf(-go));
      float cn = fv * cs[m * 16 + lj] + iv * gv;
      float hn = ov * tanhf(cn);
      cs[m * 16 + lj] = cn;
      hnxt[(size_t)m * HH + s * 16 + lj] = (_Float16)hn;
      out[((size_t)t * BB + m) * HH + s * 16 + lj] = hn;
      hv[r] = hn; cv[r] = cn;
    }
    if (t == 0) {  // final carry (hT, cT)
      #pragma unroll
      for (int r = 0; r < 4; ++r) {
        const int m = mbase + r;
        out[(size_t)TT * BB * HH + (size_t)m * HH + s * 16 + lj] = hv[r];
        out[(size_t)TT * BB * HH + (size_t)BB * HH + (size_t)m * HH + s * 16 + lj] = cv[r];
      }
    }
    // ---- distributed flag barrier (no contended RMW) ----
    __syncthreads();                   // all waves' h stores drained to L2
    if (tid == 0) {
      __builtin_amdgcn_fence(__ATOMIC_RELEASE, "agent");   // wbl2: h visible
      __hip_atomic_store(&bar[s * 32], (unsigned)(ii + 1),
                         __ATOMIC_RELAXED, __HIP_MEMORY_SCOPE_AGENT);
    }
    if (w == 0) {                      // wave 0: lane l watches wg l's flag
      const unsigned target = (unsigned)(ii + 1);
      while (true) {
        unsigned v = __hip_atomic_load(&bar[l * 32], __ATOMIC_RELAXED,
                                       __HIP_MEMORY_SCOPE_AGENT);
        if (__all(v >= target)) break;
        __builtin_amdgcn_s_sleep(1);
      }
      __builtin_amdgcn_fence(__ATOMIC_ACQUIRE, "agent");   // inv stale lines
    }
    __syncthreads();
  }
}

// ---------------- launch ----------------
extern "C" void kernel_launch(void* const* d_in, const int* in_sizes, int n_in,
                              void* d_out, int out_size, void* d_ws, size_t ws_size,
                              hipStream_t stream) {
  const float* x    = (const float*)d_in[0];
  const float* h0   = (const float*)d_in[1];
  const float* c0   = (const float*)d_in[2];
  const float* W_ih = (const float*)d_in[3];
  const float* W_hh = (const float*)d_in[4];
  const float* b_ih = (const float*)d_in[5];
  const float* b_hh = (const float*)d_in[6];
  float* out = (float*)d_out;

  char* ws = (char*)d_ws;
  size_t off = 0;
  auto take = [&](size_t bytes) -> void* {
    void* p = ws + off;
    off = (off + bytes + 255) & ~(size_t)255;
    return p;
  };
  _Float16* gx    = (_Float16*)take((size_t)TT * BB * G4 * 2);  // 268 MB
  _Float16* wih_h = (_Float16*)take((size_t)G4 * HH * 2);       // 8.4 MB
  _Float16* wsh   = (_Float16*)take((size_t)G4 * HH * 2);       // 8.4 MB
  float*    bsum  = (float*)take((size_t)G4 * 4);
  _Float16* hbuf  = (_Float16*)take((size_t)2 * BB * HH * 2);   // ping-pong h
  unsigned* bar   = (unsigned*)take(64 * 32 * 4);               // 64 flags @128B
  if (off > ws_size) return;  // workspace too small -> visible validation failure

  k_conv_wih<<<2048, 256, 0, stream>>>(W_ih, wih_h);
  k_shuf_whh<<<2048, 256, 0, stream>>>(W_hh, wsh);
  k_bsum<<<16, 256, 0, stream>>>(b_ih, b_hh, bsum);
  k_prep<<<256, 256, 0, stream>>>(h0, hbuf, bar);
  k_gemm_gx<<<8192, 256, 0, stream>>>(x, wih_h, bsum, gx);
  k_lstm_seq<<<64, 256, 0, stream>>>(gx, wsh, c0, out, hbuf, bar);
}

// Round 2
// 4840.106 us; speedup vs baseline: 2.8479x; 1.4834x over previous
//
#include <hip/hip_runtime.h>

#define TT 512
#define BB 64
#define HH 1024
#define G4 4096

typedef _Float16 h8 __attribute__((ext_vector_type(8)));
typedef float f4 __attribute__((ext_vector_type(4)));
typedef unsigned long long u64;

// ---------------- prep kernels ----------------

// W_ih fp32 -> fp16, flat copy. 4096*1024 elems, 8 per thread.
__global__ void k_conv_wih(const float* __restrict__ w, _Float16* __restrict__ o) {
  int i = blockIdx.x * 256 + threadIdx.x;          // 0..524287
  const f4* src = (const f4*)w + (size_t)i * 2;
  f4 a = src[0], b = src[1];
  h8 r;
  r[0] = (_Float16)a[0]; r[1] = (_Float16)a[1]; r[2] = (_Float16)a[2]; r[3] = (_Float16)a[3];
  r[4] = (_Float16)b[0]; r[5] = (_Float16)b[1]; r[6] = (_Float16)b[2]; r[7] = (_Float16)b[3];
  *(h8*)(o + (size_t)i * 8) = r;
}

// W_hh fp32 [4096,1024] -> fp16 shuffled into MFMA B-fragment order:
// block b = nt*32 + kt holds lane l's 8 halves W[nt*16 + (l&15)][kt*32 + (l>>4)*8 + j]
// so phase B's per-(wave,kt) load is one fully coalesced 1KB global_load_dwordx4.
__global__ void k_shuf_whh(const float* __restrict__ w, _Float16* __restrict__ o) {
  int cidx = blockIdx.x * 256 + threadIdx.x;       // 0..524287
  int b = cidx >> 6;                               // 0..8191 (256 nt * 32 kt)
  int lid = cidx & 63;
  int n = (b >> 5) * 16 + (lid & 15);
  int k0 = (b & 31) * 32 + (lid >> 4) * 8;
  const float* src = w + (size_t)n * HH + k0;
  h8 r;
  #pragma unroll
  for (int j = 0; j < 8; ++j) r[j] = (_Float16)src[j];
  *(h8*)(o + (size_t)b * 512 + lid * 8) = r;
}

__global__ void k_bsum(const float* __restrict__ bi, const float* __restrict__ bh,
                       float* __restrict__ o) {
  int i = blockIdx.x * 256 + threadIdx.x;          // 4096
  o[i] = bi[i] + bh[i];
}

// h0 fp32 -> fp16 into hbuf[0]; zero the flag array (ws is poisoned each launch).
__global__ void k_prep(const float* __restrict__ h0, _Float16* __restrict__ hbuf,
                       unsigned* __restrict__ bar) {
  int i = blockIdx.x * 256 + threadIdx.x;          // 65536
  hbuf[i] = (_Float16)h0[i];
  if (i < 2048) bar[i] = 0u;                       // 64 flags @ 128B stride
}

// ---------------- phase A: gates_x = x @ W_ih^T + (b_ih + b_hh) ----------------
// M=32768, N=4096, K=1024. 128x128 tile per 256-thread wg, BK=32, fp16 MFMA.
__global__ __launch_bounds__(256) void k_gemm_gx(
    const float* __restrict__ x, const _Float16* __restrict__ wih,
    const float* __restrict__ bsum, _Float16* __restrict__ gx) {
  __shared__ _Float16 As[128 * 40];   // pad 32->40 halves: 2-way banks only (free)
  __shared__ _Float16 Bs[128 * 40];
  const int bid = blockIdx.x;
  const int m0 = (bid >> 5) * 128;
  const int n0 = (bid & 31) * 128;
  const int tid = threadIdx.x;
  const int w = tid >> 6, l = tid & 63, q = l >> 4, lj = l & 15;
  const int wm = (w >> 1) * 64, wn = (w & 1) * 64;
  const int lrow = tid >> 1;
  const int lcol = (tid & 1) * 16;

  f4 z = {0.f, 0.f, 0.f, 0.f};
  f4 acc[4][4];
  #pragma unroll
  for (int i2 = 0; i2 < 4; ++i2)
    #pragma unroll
    for (int j2 = 0; j2 < 4; ++j2) acc[i2][j2] = z;

  for (int kt = 0; kt < 32; ++kt) {
    const int k0 = kt * 32;
    const float* xp = x + (size_t)(m0 + lrow) * HH + k0 + lcol;
    f4 a0 = ((const f4*)xp)[0];
    f4 a1 = ((const f4*)xp)[1];
    f4 a2 = ((const f4*)xp)[2];
    f4 a3 = ((const f4*)xp)[3];
    const _Float16* bp = wih + (size_t)(n0 + lrow) * HH + k0 + lcol;
    h8 b0 = ((const h8*)bp)[0];
    h8 b1 = ((const h8*)bp)[1];
    h8 lo, hi;
    lo[0] = (_Float16)a0[0]; lo[1] = (_Float16)a0[1]; lo[2] = (_Float16)a0[2]; lo[3] = (_Float16)a0[3];
    lo[4] = (_Float16)a1[0]; lo[5] = (_Float16)a1[1]; lo[6] = (_Float16)a1[2]; lo[7] = (_Float16)a1[3];
    hi[0] = (_Float16)a2[0]; hi[1] = (_Float16)a2[1]; hi[2] = (_Float16)a2[2]; hi[3] = (_Float16)a2[3];
    hi[4] = (_Float16)a3[0]; hi[5] = (_Float16)a3[1]; hi[6] = (_Float16)a3[2]; hi[7] = (_Float16)a3[3];
    __syncthreads();
    *(h8*)&As[lrow * 40 + lcol] = lo;
    *(h8*)&As[lrow * 40 + lcol + 8] = hi;
    *(h8*)&Bs[lrow * 40 + lcol] = b0;
    *(h8*)&Bs[lrow * 40 + lcol + 8] = b1;
    __syncthreads();
    h8 af[4], bf[4];
    #pragma unroll
    for (int mt = 0; mt < 4; ++mt) af[mt] = *(h8*)&As[(wm + mt * 16 + lj) * 40 + q * 8];
    #pragma unroll
    for (int nt = 0; nt < 4; ++nt) bf[nt] = *(h8*)&Bs[(wn + nt * 16 + lj) * 40 + q * 8];
    #pragma unroll
    for (int mt = 0; mt < 4; ++mt)
      #pragma unroll
      for (int nt = 0; nt < 4; ++nt)
        acc[mt][nt] = __builtin_amdgcn_mfma_f32_16x16x32_f16(af[mt], bf[nt], acc[mt][nt], 0, 0, 0);
  }
  // epilogue: add bias, store fp16. C/D layout: col=lane&15, row=(lane>>4)*4+reg.
  #pragma unroll
  for (int nt = 0; nt < 4; ++nt) {
    int n = n0 + wn + nt * 16 + lj;
    float bv = bsum[n];
    #pragma unroll
    for (int mt = 0; mt < 4; ++mt) {
      #pragma unroll
      for (int r = 0; r < 4; ++r) {
        int m = m0 + wm + mt * 16 + q * 4 + r;
        gx[(size_t)m * G4 + n] = (_Float16)(acc[mt][nt][r] + bv);
      }
    }
  }
}

// ---------------- phase B: persistent reverse scan ----------------
// 64 wgs (1/CU), wg s owns h-cols [16s,16s+16); wave w computes gate-type w.
// FENCE-FREE cross-wg h exchange: h stores/loads and flags are RELAXED
// AGENT-scope atomics (sc0/sc1: write-through / read-through at the coherence
// point). No buffer_wbl2 / buffer_inv ever -> L2 stays warm for wsh.
// Release ordering bet: vmcnt(0) (emitted by __syncthreads) on sc1 stores
// means "at coherence point"; flag post follows the barrier.
// Dependency sync: 8 h-chunks of 128 cols; chunk c is produced by wgs
// [8c,8c+8). One 64-lane ballot poll refreshes readiness of ALL chunks
// (sticky mask); per-chunk waits let a wg start GEMM before stragglers post.
__global__ __launch_bounds__(256, 1) void k_lstm_seq(
    const _Float16* __restrict__ gx, const _Float16* __restrict__ wsh,
    const float* __restrict__ c0, float* __restrict__ out,
    _Float16* __restrict__ hbuf, unsigned* __restrict__ bar) {
  __shared__ _Float16 hs[2][64 * 136]; // double-buffered chunk [64 x 128], pad 8
  __shared__ float gbuf[4 * 64 * 20];  // gate exchange, row pad 16->20 (16B-aligned)
  __shared__ float cs[64 * 20];        // persistent c slice, same pad
  const int tid = threadIdx.x;
  const int s = blockIdx.x;            // 0..63
  const int w = tid >> 6;
  const int l = tid & 63;
  const int q = l >> 4;
  const int lj = l & 15;
  const int em = tid >> 2;             // elementwise: row 0..63
  const int ec = (tid & 3) * 4;        // elementwise: col base (4 contiguous cols)

  #pragma unroll
  for (int u = 0; u < 4; ++u) {
    int e = u * 256 + tid;             // (m = e>>4, j = e&15)
    cs[(e >> 4) * 20 + (e & 15)] = c0[(size_t)(e >> 4) * HH + s * 16 + (e & 15)];
  }

  for (int ii = 0; ii < TT; ++ii) {
    const int t = TT - 1 - ii;
    const _Float16* __restrict__ hcur = hbuf + (size_t)(ii & 1) * (BB * HH);
    _Float16* __restrict__ hnxt = hbuf + (size_t)((ii + 1) & 1) * (BB * HH);
    const unsigned tgt = (unsigned)ii; // reads need producers' flag >= ii

    // ---- gx prefetch (plain cached loads, independent of flags): issue first
    const _Float16* gxb = gx + (size_t)t * BB * G4 + w * HH + s * 16;
    _Float16 gpre[16];
    #pragma unroll
    for (int mt = 0; mt < 4; ++mt)
      #pragma unroll
      for (int r = 0; r < 4; ++r)
        gpre[mt * 4 + r] = gxb[(size_t)(mt * 16 + q * 4 + r) * G4 + lj];

    // ---- readiness machinery: sticky per-wave mask of (flag[l] >= tgt)
    u64 rdy = 0;
    auto wait_chunk = [&](int c) {
      while (((rdy >> (c * 8)) & 0xFFull) != 0xFFull) {
        unsigned v = __hip_atomic_load(&bar[l * 32], __ATOMIC_RELAXED,
                                       __HIP_MEMORY_SCOPE_AGENT);
        rdy = __ballot(v >= tgt);
        if (((rdy >> (c * 8)) & 0xFFull) == 0xFFull) break;
        __builtin_amdgcn_s_sleep(1);
      }
    };
    auto load_chunk = [&](int c, u64* dst) {
      #pragma unroll
      for (int u = 0; u < 8; ++u) {
        int e = u * 256 + tid;         // 0..2047: row = e>>5, 8B unit (e&31)
        dst[u] = __hip_atomic_load(
            (const u64*)&hcur[(size_t)(e >> 5) * HH + c * 128 + (e & 31) * 4],
            __ATOMIC_RELAXED, __HIP_MEMORY_SCOPE_AGENT);
      }
    };

    f4 z = {0.f, 0.f, 0.f, 0.f};
    f4 acc[4];
    #pragma unroll
    for (int mt = 0; mt < 4; ++mt) acc[mt] = z;

    u64 pre0[8], pre1[8];
    wait_chunk(0); load_chunk(0, pre0);
    wait_chunk(1); load_chunk(1, pre1);

    #pragma unroll
    for (int ck = 0; ck < 8; ++ck) {
      u64* cur = (ck & 1) ? pre1 : pre0;
      // stage chunk ck into LDS buffer ck&1 (prior use of this buffer was
      // MFMA at ck-2, complete before sync(ck-1))
      #pragma unroll
      for (int u = 0; u < 8; ++u) {
        int e = u * 256 + tid;
        *(u64*)&hs[ck & 1][(e >> 5) * 136 + (e & 31) * 4] = cur[u];
      }
      __syncthreads();
      // 2-deep lookahead: issue chunk ck+2 loads; latency hides under 2 chunks
      // of sync+MFMA.
      if (ck < 6) { wait_chunk(ck + 2); load_chunk(ck + 2, cur); }
      #pragma unroll
      for (int kk = 0; kk < 4; ++kk) {
        int blk = (w * 64 + s) * 32 + ck * 4 + kk;
        h8 bfr = *(const h8*)&wsh[(size_t)blk * 512 + l * 8];  // L2-hot (no inv!)
        #pragma unroll
        for (int mt = 0; mt < 4; ++mt) {
          h8 afr = *(const h8*)&hs[ck & 1][(mt * 16 + lj) * 136 + kk * 32 + q * 8];
          acc[mt] = __builtin_amdgcn_mfma_f32_16x16x32_f16(afr, bfr, acc[mt], 0, 0, 0);
        }
      }
    }
    // add gates_x (registers), exchange via LDS
    #pragma unroll
    for (int mt = 0; mt < 4; ++mt) {
      #pragma unroll
      for (int r = 0; r < 4; ++r) {
        int m = mt * 16 + q * 4 + r;
        gbuf[(w * 64 + m) * 20 + lj] = acc[mt][r] + (float)gpre[mt * 4 + r];
      }
    }
    __syncthreads();
    // elementwise: thread handles (row em, cols ec..ec+3) -> h store is ONE
    // contiguous 8B relaxed agent atomic; out store is one float4.
    f4 gi4 = *(f4*)&gbuf[(0 * 64 + em) * 20 + ec];
    f4 gf4 = *(f4*)&gbuf[(1 * 64 + em) * 20 + ec];
    f4 gg4 = *(f4*)&gbuf[(2 * 64 + em) * 20 + ec];
    f4 go4 = *(f4*)&gbuf[(3 * 64 + em) * 20 + ec];
    f4 cold = *(f4*)&cs[em * 20 + ec];
    f4 hn4, cn4;
    #pragma unroll
    for (int j = 0; j < 4; ++j) {
      float iv = 1.f / (1.f + __expf(-gi4[j]));
      float fv = 1.f / (1.f + __expf(-gf4[j]));
      float gv = tanhf(gg4[j]);
      float ov = 1.f / (1.f + __expf(-go4[j]));
      float cn = fv * cold[j] + iv * gv;
      cn4[j] = cn;
      hn4[j] = ov * tanhf(cn);
    }
    *(f4*)&cs[em * 20 + ec] = cn4;
    union { _Float16 h[4]; u64 u; } pk;
    #pragma unroll
    for (int j = 0; j < 4; ++j) pk.h[j] = (_Float16)hn4[j];
    __hip_atomic_store((u64*)&hnxt[(size_t)em * HH + s * 16 + ec], pk.u,
                       __ATOMIC_RELAXED, __HIP_MEMORY_SCOPE_AGENT);
    *(f4*)&out[((size_t)t * BB + em) * HH + s * 16 + ec] = hn4;
    if (t == 0) {  // final carry (hT, cT)
      *(f4*)&out[(size_t)TT * BB * HH + (size_t)em * HH + s * 16 + ec] = hn4;
      *(f4*)&out[(size_t)TT * BB * HH + (size_t)BB * HH + (size_t)em * HH + s * 16 + ec] = cn4;
    }
    // ---- post own flag. __syncthreads drains vmcnt(0) per wave -> all sc1
    // h-stores are at the coherence point before any thread passes.
    __syncthreads();
    if (tid == 0)
      __hip_atomic_store(&bar[s * 32], (unsigned)(ii + 1), __ATOMIC_RELAXED,
                         __HIP_MEMORY_SCOPE_AGENT);
  }
}

// ---------------- launch ----------------
extern "C" void kernel_launch(void* const* d_in, const int* in_sizes, int n_in,
                              void* d_out, int out_size, void* d_ws, size_t ws_size,
                              hipStream_t stream) {
  const float* x    = (const float*)d_in[0];
  const float* h0   = (const float*)d_in[1];
  const float* c0   = (const float*)d_in[2];
  const float* W_ih = (const float*)d_in[3];
  const float* W_hh = (const float*)d_in[4];
  const float* b_ih = (const float*)d_in[5];
  const float* b_hh = (const float*)d_in[6];
  float* out = (float*)d_out;

  char* ws = (char*)d_ws;
  size_t off = 0;
  auto take = [&](size_t bytes) -> void* {
    void* p = ws + off;
    off = (off + bytes + 255) & ~(size_t)255;
    return p;
  };
  _Float16* gx    = (_Float16*)take((size_t)TT * BB * G4 * 2);  // 268 MB
  _Float16* wih_h = (_Float16*)take((size_t)G4 * HH * 2);       // 8.4 MB
  _Float16* wsh   = (_Float16*)take((size_t)G4 * HH * 2);       // 8.4 MB
  float*    bsum  = (float*)take((size_t)G4 * 4);
  _Float16* hbuf  = (_Float16*)take((size_t)2 * BB * HH * 2);   // ping-pong h
  unsigned* bar   = (unsigned*)take(64 * 32 * 4);               // 64 flags @128B
  if (off > ws_size) return;  // workspace too small -> visible validation failure

  k_conv_wih<<<2048, 256, 0, stream>>>(W_ih, wih_h);
  k_shuf_whh<<<2048, 256, 0, stream>>>(W_hh, wsh);
  k_bsum<<<16, 256, 0, stream>>>(b_ih, b_hh, bsum);
  k_prep<<<256, 256, 0, stream>>>(h0, hbuf, bar);
  k_gemm_gx<<<8192, 256, 0, stream>>>(x, wih_h, bsum, gx);
  k_lstm_seq<<<64, 256, 0, stream>>>(gx, wsh, c0, out, hbuf, bar);
}